// Round 12
// baseline (803.169 us; speedup 1.0000x reference)
//
#include <hip/hip_runtime.h>
#include <hip/hip_bf16.h>
#include <stdint.h>

typedef __hip_bfloat16 bf16;
typedef __bf16 bf16x8 __attribute__((ext_vector_type(8)));
typedef float f32x4 __attribute__((ext_vector_type(4)));

#define LQ   8192
#define DQ   768
#define DFFQ 3072
#define NFULL 16384    // single zero-padded FFT length (causal linear conv)
#define TWO_PI 6.2831853071795864769f

__device__ __forceinline__ float b2f(bf16 v) { return __bfloat162float(v); }
__device__ __forceinline__ bf16 f2b(float v) { return __float2bfloat16(v); }
__device__ __forceinline__ float ldf(const bf16& v) { return __bfloat162float(v); }
__device__ __forceinline__ float ldf(const float& v) { return v; }
__device__ __forceinline__ float2 cmul(float2 a, float2 b) {
    return make_float2(a.x * b.x - a.y * b.y, a.x * b.y + a.y * b.x);
}
__device__ __forceinline__ float2 csqr(float2 a) {
    return make_float2(a.x * a.x - a.y * a.y, 2.f * a.x * a.y);
}
__device__ __forceinline__ int rev14(int k) { return (int)(__brev((unsigned)k) >> 18); }
// LDS slot swizzle: folds bits [9:5] and [12:9] into the bank-pair bits so every
// power-of-2-stride phase stays near the b64 bandwidth floor. Bijective on [0,16384).
__device__ __forceinline__ int SWZ(int i) { return i ^ ((i >> 5) & 31) ^ ((i >> 9) & 15); }

// async global->LDS, 16 B per lane; LDS dest = wave-uniform base + lane*16
__device__ __forceinline__ void glds16(const bf16* g, unsigned short* l) {
    __builtin_amdgcn_global_load_lds(
        (const __attribute__((address_space(1))) void*)g,
        (__attribute__((address_space(3))) void*)l, 16, 0, 0);
}

// ---------------- pos (f32) -> bf16 cast ---------------------------------------
__global__ __launch_bounds__(256) void cast_f32_bf16(const float* __restrict__ in,
                                                     bf16* __restrict__ out, int n) {
    int i = (blockIdx.x * 256 + threadIdx.x) * 4;
    if (i + 3 < n) {
        float4 v = *(const float4*)(in + i);
        out[i] = f2b(v.x); out[i + 1] = f2b(v.y);
        out[i + 2] = f2b(v.z); out[i + 3] = f2b(v.w);
    }
}

// ---------------- twiddle table: tw[i] = e^{-2pi*i*i/16384}, i in [0,4096) -------
// All FFT twiddles are tw[idx] (forward) or conj(tw[idx]) (inverse) with idx<4096.
// 32 KB -> L2-resident, shared by all filter_fft/fft_conv blocks; replaces 56
// __sincosf per thread (trans-pipe bound, VALUBusy 56% in r11) with 8B loads.
__global__ __launch_bounds__(256) void gen_twiddle(float2* __restrict__ tw) {
    int i = blockIdx.x * 256 + threadIdx.x;
    if (i < 4096) {
        float ang = -(TWO_PI / 16384.f) * (float)i;
        tw[i] = make_float2(cosf(ang), sinf(ang));
    }
}

// ---------------- LayerNorm (one row of D=768 per block, 256 threads) -----------
template <typename TIN>
__global__ __launch_bounds__(256) void ln_kernel(const TIN* __restrict__ x,
                                                 const float* __restrict__ gamma,
                                                 const float* __restrict__ beta,
                                                 bf16* __restrict__ y) {
    size_t row = blockIdx.x;
    const TIN* xr = x + row * DQ;
    int tid = threadIdx.x;
    float v0 = ldf(xr[tid]), v1 = ldf(xr[tid + 256]), v2 = ldf(xr[tid + 512]);
    float s = v0 + v1 + v2;
    float sq = v0 * v0 + v1 * v1 + v2 * v2;
    for (int o = 32; o > 0; o >>= 1) {
        s += __shfl_down(s, o, 64);
        sq += __shfl_down(sq, o, 64);
    }
    __shared__ float red[8];
    __shared__ float mi[2];
    int lane = tid & 63, wid = tid >> 6;
    if (lane == 0) { red[wid] = s; red[4 + wid] = sq; }
    __syncthreads();
    if (tid == 0) {
        float ts = red[0] + red[1] + red[2] + red[3];
        float tq = red[4] + red[5] + red[6] + red[7];
        float mean = ts * (1.0f / 768.0f);
        float var = tq * (1.0f / 768.0f) - mean * mean;
        mi[0] = mean;
        mi[1] = rsqrtf(var + 1e-5f);
    }
    __syncthreads();
    float mean = mi[0], inv = mi[1];
    bf16* yr = y + row * DQ;
    yr[tid]       = f2b((v0 - mean) * inv * gamma[tid]       + beta[tid]);
    yr[tid + 256] = f2b((v1 - mean) * inv * gamma[tid + 256] + beta[tid + 256]);
    yr[tid + 512] = f2b((v2 - mean) * inv * gamma[tid + 512] + beta[tid + 512]);
}

// ------------- generic transpose (R,C) -> (C,R) to bf16, 32x32 tiles ------------
template <typename TIN>
__global__ __launch_bounds__(256) void transpose_to_bf16(const TIN* __restrict__ in,
                                                         bf16* __restrict__ out,
                                                         int R, int C) {
    __shared__ bf16 tile[32][33];
    size_t base = (size_t)blockIdx.z * (size_t)R * (size_t)C;
    int c0 = blockIdx.x * 32, r0 = blockIdx.y * 32;
    int x = threadIdx.x, ty = threadIdx.y;
    for (int i = ty; i < 32; i += 8)
        tile[i][x] = f2b(ldf(in[base + (size_t)(r0 + i) * C + c0 + x]));
    __syncthreads();
    for (int i = ty; i < 32; i += 8)
        out[base + (size_t)(c0 + i) * R + r0 + x] = tile[x][i];
}

// ------------- h (L,D) f32 -> whT (D,L) f32 with causal exp window -------------
__global__ __launch_bounds__(256) void transpose_window(const float* __restrict__ h,
                                                        const float* __restrict__ a,
                                                        float* __restrict__ whT) {
    __shared__ float tile[32][33];
    float rate = expf(a[0]);
    int d0 = blockIdx.x * 32, t0 = blockIdx.y * 32;
    int x = threadIdx.x, ty = threadIdx.y;
    for (int i = ty; i < 32; i += 8) {
        int t = t0 + i;
        tile[i][x] = h[(size_t)t * DQ + d0 + x] * expf(-(float)t * rate);
    }
    __syncthreads();
    for (int i = ty; i < 32; i += 8)
        whT[(size_t)(d0 + i) * LQ + t0 + x] = tile[x][i];
}

// ------------- convT (B,D,L) bf16 -> z2 (B,L,D) bf16 = conv + z (f32) ----------
__global__ __launch_bounds__(256) void transpose_residual(const bf16* __restrict__ convT,
                                                          const float* __restrict__ z,
                                                          bf16* __restrict__ z2) {
    __shared__ bf16 tile[32][33];
    size_t cbase = (size_t)blockIdx.z * DQ * LQ;
    size_t zbase = (size_t)blockIdx.z * LQ * DQ;
    int t0 = blockIdx.x * 32, d0 = blockIdx.y * 32;
    int x = threadIdx.x, ty = threadIdx.y;
    for (int i = ty; i < 32; i += 8)
        tile[i][x] = convT[cbase + (size_t)(d0 + i) * LQ + t0 + x];
    __syncthreads();
    for (int i = ty; i < 32; i += 8) {
        size_t idx = zbase + (size_t)(t0 + i) * DQ + d0 + x;
        z2[idx] = f2b(b2f(tile[x][i]) + z[idx]);
    }
}

// ================= radix-4 FFT-16384 in 128KB LDS (1024 threads) ===============
// r9 verified: VGPR 52, zero spill, <=4 float2 live per thread. r12: all
// twiddles from the global table (forward tw[idx], inverse conj(tw[idx]));
// mid-phase idx = l << (12-k) < 4096, P1 idx = G < 4096.

__device__ __forceinline__ void dif_bf(float2& u, float2& v, float2 tw) {
    float2 a = make_float2(u.x + v.x, u.y + v.y);
    float2 b = make_float2(u.x - v.x, u.y - v.y);
    u = a; v = cmul(b, tw);
}
__device__ __forceinline__ void dit_bf(float2& u, float2& v, float2 tw) {
    float2 tv = cmul(v, tw);
    v = make_float2(u.x - tv.x, u.y - tv.y);
    u = make_float2(u.x + tv.x, u.y + tv.y);
}
// one radix-4 DIF group (halves 2S then S); x_i at offsets i*S; w = e^{-2pi*i*l/(4S)}
__device__ __forceinline__ void dif2(float2& x0, float2& x1, float2& x2, float2& x3,
                                     float2 w) {
    float2 w2 = csqr(w);
    float2 wn = make_float2(w.y, -w.x);   // w * (-i)
    dif_bf(x0, x2, w);
    dif_bf(x1, x3, wn);
    dif_bf(x0, x1, w2);
    dif_bf(x2, x3, w2);
}
// one radix-4 DIT group (halves S then 2S); w = e^{+2pi*i*l/(4S)}
__device__ __forceinline__ void dit2(float2& x0, float2& x1, float2& x2, float2& x3,
                                     float2 w) {
    float2 w2 = csqr(w);
    float2 wp = make_float2(-w.y, w.x);   // w * (+i)
    dit_bf(x0, x1, w2);
    dit_bf(x2, x3, w2);
    dit_bf(x0, x2, w);
    dit_bf(x1, x3, wp);
}

// middle forward phases k=10..0 (S=1024..1): natural-in, bit-reversed-out overall
__device__ __forceinline__ void fwd_mid(float2* s, const float2* __restrict__ tw) {
    const int tid = threadIdx.x;
#pragma unroll
    for (int k = 10; k >= 0; k -= 2) {
        const int S = 1 << k;
#pragma unroll
        for (int g2 = 0; g2 < 4; g2++) {
            int G = tid + (g2 << 10);
            int l = G & (S - 1);
            int base = ((G >> k) << (k + 2)) | l;
            float2 x0 = s[SWZ(base)];
            float2 x1 = s[SWZ(base + S)];
            float2 x2 = s[SWZ(base + 2 * S)];
            float2 x3 = s[SWZ(base + 3 * S)];
            float2 w = tw[l << (12 - k)];
            dif2(x0, x1, x2, x3, w);
            s[SWZ(base)] = x0;
            s[SWZ(base + S)] = x1;
            s[SWZ(base + 2 * S)] = x2;
            s[SWZ(base + 3 * S)] = x3;
        }
        __syncthreads();
    }
}
// middle inverse phases k=0..10: bit-reversed-in, (before last phase) natural-out
__device__ __forceinline__ void inv_mid(float2* s, const float2* __restrict__ tw) {
    const int tid = threadIdx.x;
#pragma unroll
    for (int k = 0; k <= 10; k += 2) {
        const int S = 1 << k;
#pragma unroll
        for (int g2 = 0; g2 < 4; g2++) {
            int G = tid + (g2 << 10);
            int l = G & (S - 1);
            int base = ((G >> k) << (k + 2)) | l;
            float2 x0 = s[SWZ(base)];
            float2 x1 = s[SWZ(base + S)];
            float2 x2 = s[SWZ(base + 2 * S)];
            float2 x3 = s[SWZ(base + 3 * S)];
            float2 t = tw[l << (12 - k)];
            float2 w = make_float2(t.x, -t.y);        // conj -> e^{+i...}
            dit2(x0, x1, x2, x3, w);
            s[SWZ(base)] = x0;
            s[SWZ(base + S)] = x1;
            s[SWZ(base + 2 * S)] = x2;
            s[SWZ(base + 3 * S)] = x3;
        }
        __syncthreads();
    }
}

// ------------- filter spectrum: whT (D,L) f32 -> H (D, 8193) complex ------------
// Two real channels packed re/im into one FFT-16384 (zero-padded upper half);
// Hermitian split -> H0[m], H1[m] for m = 0..8192.
__global__ __launch_bounds__(1024) void filter_fft(const float* __restrict__ whT,
                                                   const float2* __restrict__ tw,
                                                   float2* __restrict__ H) {
    __shared__ float2 s[NFULL];
    int p = blockIdx.x;
    int d0 = 2 * p, d1 = d0 + 1;
    const float* g0 = whT + (size_t)d0 * LQ;
    const float* g1 = whT + (size_t)d1 * LQ;
    float2* H0 = H + (size_t)d0 * 8193;
    float2* H1 = H + (size_t)d1 * 8193;
    const int tid = threadIdx.x;

    // P1 (halves 8192,4096, S=4096) fused with global load; x2=x3=0 (zero pad)
#pragma unroll
    for (int g2 = 0; g2 < 4; g2++) {
        int G = tid + (g2 << 10);
        float2 x0 = make_float2(g0[G], g1[G]);
        float2 x1 = make_float2(g0[G + 4096], g1[G + 4096]);
        float2 w = tw[G];
        float2 w2 = csqr(w);
        float2 wn = make_float2(w.y, -w.x);
        float2 x2 = cmul(x0, w);     // dif_bf(x0, 0, w)
        float2 x3 = cmul(x1, wn);    // dif_bf(x1, 0, wn)
        dif_bf(x0, x1, w2);
        dif_bf(x2, x3, w2);
        s[SWZ(G)] = x0;
        s[SWZ(G + 4096)] = x1;
        s[SWZ(G + 8192)] = x2;
        s[SWZ(G + 12288)] = x3;
    }
    __syncthreads();
    fwd_mid(s, tw);
    // Hermitian split: C[m] -> H0, H1 (bin m lives at position rev14(m))
    for (int m = tid; m <= 8192; m += 1024) {
        int p1 = SWZ(rev14(m)), p2 = SWZ(rev14((NFULL - m) & (NFULL - 1)));
        float2 u = s[p1], v = s[p2];
        H0[m] = make_float2(0.5f * (u.x + v.x), 0.5f * (u.y - v.y));
        H1[m] = make_float2(0.5f * (u.y + v.y), 0.5f * (v.x - u.x));
    }
}

// ------------- fused causal conv: xlnT (B,D,L) bf16 -> convT (B,D,L) bf16 -------
__global__ __launch_bounds__(1024) void fft_conv(const bf16* __restrict__ xlnT,
                                                 const float2* __restrict__ H,
                                                 const float2* __restrict__ tw,
                                                 bf16* __restrict__ convT) {
    __shared__ float2 s[NFULL];
    int wg = blockIdx.x;            // b * 384 + pair
    int b = wg / 384, p = wg % 384;
    int d0 = 2 * p, d1 = d0 + 1;
    const bf16* g0 = xlnT + ((size_t)b * DQ + d0) * LQ;
    const bf16* g1 = g0 + LQ;
    const float2* H0 = H + (size_t)d0 * 8193;
    const float2* H1 = H + (size_t)d1 * 8193;
    bf16* o0 = convT + ((size_t)b * DQ + d0) * LQ;
    bf16* o1 = o0 + LQ;
    const int tid = threadIdx.x;

    // ---- forward: P1 fused with global load (upper half zero-padded) ----
#pragma unroll
    for (int g2 = 0; g2 < 4; g2++) {
        int G = tid + (g2 << 10);
        float2 x0 = make_float2(b2f(g0[G]), b2f(g1[G]));
        float2 x1 = make_float2(b2f(g0[G + 4096]), b2f(g1[G + 4096]));
        float2 w = tw[G];
        float2 w2 = csqr(w);
        float2 wn = make_float2(w.y, -w.x);
        float2 x2 = cmul(x0, w);
        float2 x3 = cmul(x1, wn);
        dif_bf(x0, x1, w2);
        dif_bf(x2, x3, w2);
        s[SWZ(G)] = x0;
        s[SWZ(G + 4096)] = x1;
        s[SWZ(G + 8192)] = x2;
        s[SWZ(G + 12288)] = x3;
    }
    __syncthreads();
    fwd_mid(s, tw);

    // ---- pointwise: split channels, multiply by H, repack ----
    for (int m = tid; m <= 8192; m += 1024) {
        int p1 = SWZ(rev14(m)), p2 = SWZ(rev14((NFULL - m) & (NFULL - 1)));
        float2 u = s[p1], v = s[p2];
        float2 X0 = make_float2(0.5f * (u.x + v.x), 0.5f * (u.y - v.y));
        float2 X1 = make_float2(0.5f * (u.y + v.y), 0.5f * (v.x - u.x));
        float2 Y0 = cmul(H0[m], X0);
        float2 Y1 = cmul(H1[m], X1);
        s[p1] = make_float2(Y0.x - Y1.y, Y0.y + Y1.x);                  // Y0 + i*Y1
        s[p2] = make_float2(Y0.x + Y1.y, Y1.x - Y0.y);                  // conj(Y0)+i*conj(Y1)
    }
    __syncthreads();

    // ---- inverse: middle phases, then P1' fused with output store ----
    inv_mid(s, tw);
    {
        const float sc = 1.0f / (float)NFULL;
#pragma unroll
        for (int g2 = 0; g2 < 4; g2++) {
            int G = tid + (g2 << 10);
            float2 x0 = s[SWZ(G)];
            float2 x1 = s[SWZ(G + 4096)];
            float2 x2 = s[SWZ(G + 8192)];
            float2 x3 = s[SWZ(G + 12288)];
            float2 t = tw[G];
            float2 w = make_float2(t.x, -t.y);       // e^{+2pi*i*G/16384}
            float2 w2 = csqr(w);
            dit_bf(x0, x1, w2);          // half=4096 stage
            dit_bf(x2, x3, w2);
            // half=8192 stage, keep only t<8192 outputs (causal conv tail dropped)
            float2 t0 = cmul(x2, w);
            float2 wp = make_float2(-w.y, w.x);
            float2 t1 = cmul(x3, wp);
            o0[G]        = f2b((x0.x + t0.x) * sc);
            o1[G]        = f2b((x0.y + t0.y) * sc);
            o0[G + 4096] = f2b((x1.x + t1.x) * sc);
            o1[G + 4096] = f2b((x1.y + t1.y) * sc);
        }
    }
}

// ---------------- bf16 MFMA GEMM: C = epi(A(M,K) @ Bt(N,K)^T + bias) ------------
// 128x128 tile, BK=32, 256 threads (4 waves, 2x2), 4x4 16x16x32 MFMA per wave.
// r12: REVERTED to r10's 2-phase double-buffer (32KB LDS, 5 blocks/CU).
// r11's ring-3 + counted vmcnt traded TLP (5->3 blocks/CU) for pipeline depth
// and came out neutral-to-worse (768 -> 781 us); cross-wave TLP was already
// hiding the load latency this structure can hide.
#define BMT 128
#define BNT 128
#define BKT 32

template <int EPI>  // 0: silu->bf16   1: plain->f32   2: +res(bf16)->f32
__global__ __launch_bounds__(256) void gemm_bt(const bf16* __restrict__ A,
                                               const bf16* __restrict__ Bt,
                                               const float* __restrict__ bias,
                                               const bf16* __restrict__ res,
                                               void* __restrict__ out,
                                               int M, int N, int K) {
    __shared__ __align__(16) unsigned short As[2][BMT * BKT];
    __shared__ __align__(16) unsigned short Bs[2][BNT * BKT];
    int tid = threadIdx.x;
    int m0 = blockIdx.y * BMT, n0 = blockIdx.x * BNT;
    int lane = tid & 63, w = tid >> 6;
    int wm = w >> 1, wn = w & 1;
    int colq = lane & 15, quad = lane >> 4;

    f32x4 acc[4][4];
    for (int i = 0; i < 4; i++)
        for (int j = 0; j < 4; j++) acc[i][j] = (f32x4){0.f, 0.f, 0.f, 0.f};

    int lrow = lane >> 2, lcol = (lane & 3) * 8;
    int ch0 = w * 2, ch1 = w * 2 + 1;
    const bf16* ga0 = A + (size_t)(m0 + ch0 * 16 + lrow) * K + lcol;
    const bf16* ga1 = A + (size_t)(m0 + ch1 * 16 + lrow) * K + lcol;
    const bf16* gb0 = Bt + (size_t)(n0 + ch0 * 16 + lrow) * K + lcol;
    const bf16* gb1 = Bt + (size_t)(n0 + ch1 * 16 + lrow) * K + lcol;

    const int nk = K / BKT;
    // prologue: stage K-tile 0 into buffer 0
    glds16(ga0, &As[0][ch0 * 512]);
    glds16(ga1, &As[0][ch1 * 512]);
    glds16(gb0, &Bs[0][ch0 * 512]);
    glds16(gb1, &Bs[0][ch1 * 512]);
    __syncthreads();                 // vmcnt(0) drain: buffer 0 ready

    int cur = 0;
    for (int kb = 0; kb < nk; kb++) {
        // issue next-tile loads first; their flight hides under this tile's compute
        if (kb + 1 < nk) {
            int k1 = (kb + 1) * BKT;
            int nb = cur ^ 1;
            glds16(ga0 + k1, &As[nb][ch0 * 512]);
            glds16(ga1 + k1, &As[nb][ch1 * 512]);
            glds16(gb0 + k1, &Bs[nb][ch0 * 512]);
            glds16(gb1 + k1, &Bs[nb][ch1 * 512]);
        }
        bf16x8 af[4], bfr[4];
        for (int i = 0; i < 4; i++) {
            int mrow = wm * 64 + i * 16 + colq;
            af[i] = *(const bf16x8*)(&As[cur][mrow * BKT + quad * 8]);
            int nrow = wn * 64 + i * 16 + colq;
            bfr[i] = *(const bf16x8*)(&Bs[cur][nrow * BKT + quad * 8]);
        }
        for (int i = 0; i < 4; i++)
            for (int j = 0; j < 4; j++)
                acc[i][j] = __builtin_amdgcn_mfma_f32_16x16x32_bf16(af[i], bfr[j], acc[i][j], 0, 0, 0);
        __syncthreads();             // reads of buf[cur] done + next tile landed
        cur ^= 1;
    }
    for (int j = 0; j < 4; j++) {
        int n = n0 + wn * 64 + j * 16 + colq;
        float bv = bias[n];
        for (int i = 0; i < 4; i++) {
            int mbase = m0 + wm * 64 + i * 16 + quad * 4;
            for (int r = 0; r < 4; r++) {
                int m = mbase + r;
                float v = acc[i][j][r] + bv;
                size_t idx = (size_t)m * N + n;
                if (EPI == 0) {
                    ((bf16*)out)[idx] = f2b(v / (1.0f + expf(-v)));
                } else if (EPI == 1) {
                    ((float*)out)[idx] = v;
                } else {
                    ((float*)out)[idx] = v + b2f(res[idx]);
                }
            }
        }
    }
}

extern "C" void kernel_launch(void* const* d_in, const int* in_sizes, int n_in,
                              void* d_out, int out_size, void* d_ws, size_t ws_size,
                              hipStream_t stream) {
    (void)in_sizes; (void)n_in; (void)out_size; (void)ws_size;
    const float* z     = (const float*)d_in[0];
    const float* pos   = (const float*)d_in[1];
    const float* a     = (const float*)d_in[2];
    const float* w1p   = (const float*)d_in[3];
    const float* b1p   = (const float*)d_in[4];
    const float* w2p   = (const float*)d_in[5];
    const float* b2p   = (const float*)d_in[6];
    const float* w1    = (const float*)d_in[7];
    const float* b1    = (const float*)d_in[8];
    const float* w2    = (const float*)d_in[9];
    const float* b2    = (const float*)d_in[10];
    const float* gamma = (const float*)d_in[11];
    const float* beta  = (const float*)d_in[12];
    float* out = (float*)d_out;
    char* ws = (char*)d_ws;

    // ---- compact arena, 144,709,632 bytes total (lifetime-multiplexed) ----
    bf16*   w1T   = (bf16*)  (ws + 0);           //  4,718,592 (persistent)
    bf16*   w2T   = (bf16*)  (ws + 4718592);     //  4,718,592 (persistent)
    bf16*   w1pT  = (bf16*)  (ws + 9437184);     //  dead after pos-gemm1
    float2* twid  = (float2*)(ws + 9437184);     //  32KB twiddle table over dead w1pT
    bf16*   w2pT  = (bf16*)  (ws + 14155776);    //  dead after pos-gemm2
    bf16*   xlnT  = (bf16*)  (ws + 18874368);    // (B,D,L) bf16, 25.2M (ln..fft_conv)
    // R1 @44,040,192 (50,337,792): act1 (pos-FFN), then Hbuf (filter_fft..fft_conv)
    bf16*   act1  = (bf16*)  (ws + 44040192);    // (L,DFF) bf16
    float2* Hbuf  = (float2*)(ws + 44040192);    // (D,8193) cplx
    // R2 @94,377,984: two 25MB half-slots, time-multiplexed
    bf16*   xln   = (bf16*)  (ws + 94377984);    // (B,L,D) bf16 (ln..transpose)
    bf16*   posb  = (bf16*)  (ws + 119543808);   // (L,D) bf16 (cast..pos-gemm1)
    float*  h     = (float*) (ws + 119543808);   // (L,D) f32 (pos-gemm2..window); posb dead
    float*  whT   = (float*) (ws + 94377984);    // (D,L) f32 (window..filter_fft); xln dead
    bf16*   convT = (bf16*)  (ws + 119543808);   // (B,D,L) bf16 (fft_conv..residual); h dead
    bf16*   z2    = (bf16*)  (ws + 94377984);    // (B,L,D) bf16 (residual..end); whT dead
    bf16*   xb    = (bf16*)  (ws + 119543808);   // (B,L,D) bf16 (ln2..ffn); convT dead
    bf16*   act2  = (bf16*)  (ws + 18874368);    // (L,DFF) bf16 over dead xlnT+Hbuf

    dim3 tb(32, 8);
    // pre-transpose weights (K,N) f32 -> (N,K) bf16
    transpose_to_bf16<float><<<dim3(DFFQ / 32, DQ / 32, 1), tb, 0, stream>>>(w1p, w1pT, DQ, DFFQ);
    transpose_to_bf16<float><<<dim3(DQ / 32, DFFQ / 32, 1), tb, 0, stream>>>(w2p, w2pT, DFFQ, DQ);
    transpose_to_bf16<float><<<dim3(DFFQ / 32, DQ / 32, 1), tb, 0, stream>>>(w1, w1T, DQ, DFFQ);
    transpose_to_bf16<float><<<dim3(DQ / 32, DFFQ / 32, 1), tb, 0, stream>>>(w2, w2T, DFFQ, DQ);
    // pos f32 -> bf16
    cast_f32_bf16<<<(LQ * DQ / 4 + 255) / 256, 256, 0, stream>>>(pos, posb, LQ * DQ);
    // LN(z) -> xln, then transpose to (B,D,L)
    ln_kernel<float><<<2 * LQ, 256, 0, stream>>>(z, gamma, beta, xln);
    transpose_to_bf16<bf16><<<dim3(DQ / 32, LQ / 32, 2), tb, 0, stream>>>(xln, xlnT, LQ, DQ);
    // pos FFN -> h
    gemm_bt<0><<<dim3(DFFQ / BNT, LQ / BMT), 256, 0, stream>>>(posb, w1pT, b1p, nullptr, act1, LQ, DFFQ, DQ);
    // twiddle table into the now-dead w1pT slot
    gen_twiddle<<<16, 256, 0, stream>>>(twid);
    gemm_bt<1><<<dim3(DQ / BNT, LQ / BMT), 256, 0, stream>>>(act1, w2pT, b2p, nullptr, h, LQ, DQ, DFFQ);
    // window * h, transposed -> whT
    transpose_window<<<dim3(DQ / 32, LQ / 32), tb, 0, stream>>>(h, a, whT);
    // filter spectrum -> Hbuf (overwrites act1, dead)
    filter_fft<<<DQ / 2, 1024, 0, stream>>>(whT, twid, Hbuf);
    // fused FFT conv -> convT
    fft_conv<<<2 * (DQ / 2), 1024, 0, stream>>>(xlnT, Hbuf, twid, convT);
    // z2 = conv + z (overwrites whT slot, dead)
    transpose_residual<<<dim3(LQ / 32, DQ / 32, 2), tb, 0, stream>>>(convT, z, z2);
    // LN(z2) -> xb (overwrites convT slot, dead)
    ln_kernel<bf16><<<2 * LQ, 256, 0, stream>>>(z2, gamma, beta, xb);
    // main FFN + residual -> out, batch-halved so act2 fits
    for (int b = 0; b < 2; b++) {
        const bf16* xbh = xb + (size_t)b * LQ * DQ;
        const bf16* z2h = z2 + (size_t)b * LQ * DQ;
        float* outh = out + (size_t)b * LQ * DQ;
        gemm_bt<0><<<dim3(DFFQ / BNT, LQ / BMT), 256, 0, stream>>>(xbh, w1T, b1, nullptr, act2, LQ, DFFQ, DQ);
        gemm_bt<2><<<dim3(DQ / BNT, LQ / BMT), 256, 0, stream>>>(act2, w2T, b2, z2h, outh, LQ, DQ, DFFQ);
    }
}

// Round 13
// 767.456 us; speedup vs baseline: 1.0465x; 1.0465x over previous
//
#include <hip/hip_runtime.h>
#include <hip/hip_bf16.h>
#include <stdint.h>

typedef __hip_bfloat16 bf16;
typedef __bf16 bf16x8 __attribute__((ext_vector_type(8)));
typedef float f32x4 __attribute__((ext_vector_type(4)));

#define LQ   8192
#define DQ   768
#define DFFQ 3072
#define NFULL 16384    // single zero-padded FFT length (causal linear conv)
#define TWO_PI 6.2831853071795864769f

__device__ __forceinline__ float b2f(bf16 v) { return __bfloat162float(v); }
__device__ __forceinline__ bf16 f2b(float v) { return __float2bfloat16(v); }
__device__ __forceinline__ float ldf(const bf16& v) { return __bfloat162float(v); }
__device__ __forceinline__ float ldf(const float& v) { return v; }
__device__ __forceinline__ float2 cmul(float2 a, float2 b) {
    return make_float2(a.x * b.x - a.y * b.y, a.x * b.y + a.y * b.x);
}
__device__ __forceinline__ float2 csqr(float2 a) {
    return make_float2(a.x * a.x - a.y * a.y, 2.f * a.x * a.y);
}
__device__ __forceinline__ int rev14(int k) { return (int)(__brev((unsigned)k) >> 18); }
// LDS slot swizzle: folds bits [9:5] and [12:9] into the bank-pair bits so every
// power-of-2-stride phase stays near the b64 bandwidth floor. Bijective on [0,16384).
__device__ __forceinline__ int SWZ(int i) { return i ^ ((i >> 5) & 31) ^ ((i >> 9) & 15); }

// async global->LDS, 16 B per lane; LDS dest = wave-uniform base + lane*16
__device__ __forceinline__ void glds16(const bf16* g, unsigned short* l) {
    __builtin_amdgcn_global_load_lds(
        (const __attribute__((address_space(1))) void*)g,
        (__attribute__((address_space(3))) void*)l, 16, 0, 0);
}

// ---------------- pos (f32) -> bf16 cast ---------------------------------------
__global__ __launch_bounds__(256) void cast_f32_bf16(const float* __restrict__ in,
                                                     bf16* __restrict__ out, int n) {
    int i = (blockIdx.x * 256 + threadIdx.x) * 4;
    if (i + 3 < n) {
        float4 v = *(const float4*)(in + i);
        out[i] = f2b(v.x); out[i + 1] = f2b(v.y);
        out[i + 2] = f2b(v.z); out[i + 3] = f2b(v.w);
    }
}

// ---------------- twiddle table: tw[i] = e^{-2pi*i*i/16384}, i in [0,4096) -------
// 32 KB, L2-resident; replaces 56 __sincosf/thread (r12 verified: VALUBusy
// 56 -> 37.5%). SPILL WARNING (r12 lesson): do NOT unroll the g2 group loops —
// unrolling makes 4 groups' state live at once (16 float2 + 4 twiddles) and
// reintroduces the r1-r6 scratch spill (+107 MB WRITE, VGPR 52->64).
__global__ __launch_bounds__(256) void gen_twiddle(float2* __restrict__ tw) {
    int i = blockIdx.x * 256 + threadIdx.x;
    if (i < 4096) {
        float ang = -(TWO_PI / 16384.f) * (float)i;
        tw[i] = make_float2(cosf(ang), sinf(ang));
    }
}

// ---------------- LayerNorm (one row of D=768 per block, 256 threads) -----------
template <typename TIN>
__global__ __launch_bounds__(256) void ln_kernel(const TIN* __restrict__ x,
                                                 const float* __restrict__ gamma,
                                                 const float* __restrict__ beta,
                                                 bf16* __restrict__ y) {
    size_t row = blockIdx.x;
    const TIN* xr = x + row * DQ;
    int tid = threadIdx.x;
    float v0 = ldf(xr[tid]), v1 = ldf(xr[tid + 256]), v2 = ldf(xr[tid + 512]);
    float s = v0 + v1 + v2;
    float sq = v0 * v0 + v1 * v1 + v2 * v2;
    for (int o = 32; o > 0; o >>= 1) {
        s += __shfl_down(s, o, 64);
        sq += __shfl_down(sq, o, 64);
    }
    __shared__ float red[8];
    __shared__ float mi[2];
    int lane = tid & 63, wid = tid >> 6;
    if (lane == 0) { red[wid] = s; red[4 + wid] = sq; }
    __syncthreads();
    if (tid == 0) {
        float ts = red[0] + red[1] + red[2] + red[3];
        float tq = red[4] + red[5] + red[6] + red[7];
        float mean = ts * (1.0f / 768.0f);
        float var = tq * (1.0f / 768.0f) - mean * mean;
        mi[0] = mean;
        mi[1] = rsqrtf(var + 1e-5f);
    }
    __syncthreads();
    float mean = mi[0], inv = mi[1];
    bf16* yr = y + row * DQ;
    yr[tid]       = f2b((v0 - mean) * inv * gamma[tid]       + beta[tid]);
    yr[tid + 256] = f2b((v1 - mean) * inv * gamma[tid + 256] + beta[tid + 256]);
    yr[tid + 512] = f2b((v2 - mean) * inv * gamma[tid + 512] + beta[tid + 512]);
}

// ------------- generic transpose (R,C) -> (C,R) to bf16, 32x32 tiles ------------
template <typename TIN>
__global__ __launch_bounds__(256) void transpose_to_bf16(const TIN* __restrict__ in,
                                                         bf16* __restrict__ out,
                                                         int R, int C) {
    __shared__ bf16 tile[32][33];
    size_t base = (size_t)blockIdx.z * (size_t)R * (size_t)C;
    int c0 = blockIdx.x * 32, r0 = blockIdx.y * 32;
    int x = threadIdx.x, ty = threadIdx.y;
    for (int i = ty; i < 32; i += 8)
        tile[i][x] = f2b(ldf(in[base + (size_t)(r0 + i) * C + c0 + x]));
    __syncthreads();
    for (int i = ty; i < 32; i += 8)
        out[base + (size_t)(c0 + i) * R + r0 + x] = tile[x][i];
}

// ------------- h (L,D) f32 -> whT (D,L) f32 with causal exp window -------------
__global__ __launch_bounds__(256) void transpose_window(const float* __restrict__ h,
                                                        const float* __restrict__ a,
                                                        float* __restrict__ whT) {
    __shared__ float tile[32][33];
    float rate = expf(a[0]);
    int d0 = blockIdx.x * 32, t0 = blockIdx.y * 32;
    int x = threadIdx.x, ty = threadIdx.y;
    for (int i = ty; i < 32; i += 8) {
        int t = t0 + i;
        tile[i][x] = h[(size_t)t * DQ + d0 + x] * expf(-(float)t * rate);
    }
    __syncthreads();
    for (int i = ty; i < 32; i += 8)
        whT[(size_t)(d0 + i) * LQ + t0 + x] = tile[x][i];
}

// ------------- convT (B,D,L) bf16 -> z2 (B,L,D) bf16 = conv + z (f32) ----------
__global__ __launch_bounds__(256) void transpose_residual(const bf16* __restrict__ convT,
                                                          const float* __restrict__ z,
                                                          bf16* __restrict__ z2) {
    __shared__ bf16 tile[32][33];
    size_t cbase = (size_t)blockIdx.z * DQ * LQ;
    size_t zbase = (size_t)blockIdx.z * LQ * DQ;
    int t0 = blockIdx.x * 32, d0 = blockIdx.y * 32;
    int x = threadIdx.x, ty = threadIdx.y;
    for (int i = ty; i < 32; i += 8)
        tile[i][x] = convT[cbase + (size_t)(d0 + i) * LQ + t0 + x];
    __syncthreads();
    for (int i = ty; i < 32; i += 8) {
        size_t idx = zbase + (size_t)(t0 + i) * DQ + d0 + x;
        z2[idx] = f2b(b2f(tile[x][i]) + z[idx]);
    }
}

// ================= radix-4 FFT-16384 in 128KB LDS (1024 threads) ===============
// r9 verified: VGPR 52, zero spill, <=4 float2 live per thread (one radix-4
// group at a time, groups SEQUENTIAL — never unroll the g2 loop, see r12).
// Twiddles from the global table: forward tw[idx], inverse conj(tw[idx]).

__device__ __forceinline__ void dif_bf(float2& u, float2& v, float2 tw) {
    float2 a = make_float2(u.x + v.x, u.y + v.y);
    float2 b = make_float2(u.x - v.x, u.y - v.y);
    u = a; v = cmul(b, tw);
}
__device__ __forceinline__ void dit_bf(float2& u, float2& v, float2 tw) {
    float2 tv = cmul(v, tw);
    v = make_float2(u.x - tv.x, u.y - tv.y);
    u = make_float2(u.x + tv.x, u.y + tv.y);
}
// one radix-4 DIF group (halves 2S then S); x_i at offsets i*S; w = e^{-2pi*i*l/(4S)}
__device__ __forceinline__ void dif2(float2& x0, float2& x1, float2& x2, float2& x3,
                                     float2 w) {
    float2 w2 = csqr(w);
    float2 wn = make_float2(w.y, -w.x);   // w * (-i)
    dif_bf(x0, x2, w);
    dif_bf(x1, x3, wn);
    dif_bf(x0, x1, w2);
    dif_bf(x2, x3, w2);
}
// one radix-4 DIT group (halves S then 2S); w = e^{+2pi*i*l/(4S)}
__device__ __forceinline__ void dit2(float2& x0, float2& x1, float2& x2, float2& x3,
                                     float2 w) {
    float2 w2 = csqr(w);
    float2 wp = make_float2(-w.y, w.x);   // w * (+i)
    dit_bf(x0, x1, w2);
    dit_bf(x2, x3, w2);
    dit_bf(x0, x2, w);
    dit_bf(x1, x3, wp);
}

// middle forward phases k=10..0 (S=1024..1): natural-in, bit-reversed-out overall
__device__ __forceinline__ void fwd_mid(float2* s, const float2* __restrict__ tw) {
    const int tid = threadIdx.x;
#pragma unroll
    for (int k = 10; k >= 0; k -= 2) {
        const int S = 1 << k;
        for (int g2 = 0; g2 < 4; g2++) {   // sequential groups: keep live state small
            int G = tid + (g2 << 10);
            int l = G & (S - 1);
            int base = ((G >> k) << (k + 2)) | l;
            float2 x0 = s[SWZ(base)];
            float2 x1 = s[SWZ(base + S)];
            float2 x2 = s[SWZ(base + 2 * S)];
            float2 x3 = s[SWZ(base + 3 * S)];
            float2 w = tw[l << (12 - k)];
            dif2(x0, x1, x2, x3, w);
            s[SWZ(base)] = x0;
            s[SWZ(base + S)] = x1;
            s[SWZ(base + 2 * S)] = x2;
            s[SWZ(base + 3 * S)] = x3;
        }
        __syncthreads();
    }
}
// middle inverse phases k=0..10: bit-reversed-in, (before last phase) natural-out
__device__ __forceinline__ void inv_mid(float2* s, const float2* __restrict__ tw) {
    const int tid = threadIdx.x;
#pragma unroll
    for (int k = 0; k <= 10; k += 2) {
        const int S = 1 << k;
        for (int g2 = 0; g2 < 4; g2++) {   // sequential groups: keep live state small
            int G = tid + (g2 << 10);
            int l = G & (S - 1);
            int base = ((G >> k) << (k + 2)) | l;
            float2 x0 = s[SWZ(base)];
            float2 x1 = s[SWZ(base + S)];
            float2 x2 = s[SWZ(base + 2 * S)];
            float2 x3 = s[SWZ(base + 3 * S)];
            float2 t = tw[l << (12 - k)];
            float2 w = make_float2(t.x, -t.y);        // conj -> e^{+i...}
            dit2(x0, x1, x2, x3, w);
            s[SWZ(base)] = x0;
            s[SWZ(base + S)] = x1;
            s[SWZ(base + 2 * S)] = x2;
            s[SWZ(base + 3 * S)] = x3;
        }
        __syncthreads();
    }
}

// ------------- filter spectrum: whT (D,L) f32 -> H (D, 8193) complex ------------
// Two real channels packed re/im into one FFT-16384 (zero-padded upper half);
// Hermitian split -> H0[m], H1[m] for m = 0..8192.
__global__ __launch_bounds__(1024) void filter_fft(const float* __restrict__ whT,
                                                   const float2* __restrict__ tw,
                                                   float2* __restrict__ H) {
    __shared__ float2 s[NFULL];
    int p = blockIdx.x;
    int d0 = 2 * p, d1 = d0 + 1;
    const float* g0 = whT + (size_t)d0 * LQ;
    const float* g1 = whT + (size_t)d1 * LQ;
    float2* H0 = H + (size_t)d0 * 8193;
    float2* H1 = H + (size_t)d1 * 8193;
    const int tid = threadIdx.x;

    // P1 (halves 8192,4096, S=4096) fused with global load; x2=x3=0 (zero pad)
    for (int g2 = 0; g2 < 4; g2++) {
        int G = tid + (g2 << 10);
        float2 x0 = make_float2(g0[G], g1[G]);
        float2 x1 = make_float2(g0[G + 4096], g1[G + 4096]);
        float2 w = tw[G];
        float2 w2 = csqr(w);
        float2 wn = make_float2(w.y, -w.x);
        float2 x2 = cmul(x0, w);     // dif_bf(x0, 0, w)
        float2 x3 = cmul(x1, wn);    // dif_bf(x1, 0, wn)
        dif_bf(x0, x1, w2);
        dif_bf(x2, x3, w2);
        s[SWZ(G)] = x0;
        s[SWZ(G + 4096)] = x1;
        s[SWZ(G + 8192)] = x2;
        s[SWZ(G + 12288)] = x3;
    }
    __syncthreads();
    fwd_mid(s, tw);
    // Hermitian split: C[m] -> H0, H1 (bin m lives at position rev14(m))
    for (int m = tid; m <= 8192; m += 1024) {
        int p1 = SWZ(rev14(m)), p2 = SWZ(rev14((NFULL - m) & (NFULL - 1)));
        float2 u = s[p1], v = s[p2];
        H0[m] = make_float2(0.5f * (u.x + v.x), 0.5f * (u.y - v.y));
        H1[m] = make_float2(0.5f * (u.y + v.y), 0.5f * (v.x - u.x));
    }
}

// ------------- fused causal conv: xlnT (B,D,L) bf16 -> convT (B,D,L) bf16 -------
__global__ __launch_bounds__(1024) void fft_conv(const bf16* __restrict__ xlnT,
                                                 const float2* __restrict__ H,
                                                 const float2* __restrict__ tw,
                                                 bf16* __restrict__ convT) {
    __shared__ float2 s[NFULL];
    int wg = blockIdx.x;            // b * 384 + pair
    int b = wg / 384, p = wg % 384;
    int d0 = 2 * p, d1 = d0 + 1;
    const bf16* g0 = xlnT + ((size_t)b * DQ + d0) * LQ;
    const bf16* g1 = g0 + LQ;
    const float2* H0 = H + (size_t)d0 * 8193;
    const float2* H1 = H + (size_t)d1 * 8193;
    bf16* o0 = convT + ((size_t)b * DQ + d0) * LQ;
    bf16* o1 = o0 + LQ;
    const int tid = threadIdx.x;

    // ---- forward: P1 fused with global load (upper half zero-padded) ----
    for (int g2 = 0; g2 < 4; g2++) {
        int G = tid + (g2 << 10);
        float2 x0 = make_float2(b2f(g0[G]), b2f(g1[G]));
        float2 x1 = make_float2(b2f(g0[G + 4096]), b2f(g1[G + 4096]));
        float2 w = tw[G];
        float2 w2 = csqr(w);
        float2 wn = make_float2(w.y, -w.x);
        float2 x2 = cmul(x0, w);
        float2 x3 = cmul(x1, wn);
        dif_bf(x0, x1, w2);
        dif_bf(x2, x3, w2);
        s[SWZ(G)] = x0;
        s[SWZ(G + 4096)] = x1;
        s[SWZ(G + 8192)] = x2;
        s[SWZ(G + 12288)] = x3;
    }
    __syncthreads();
    fwd_mid(s, tw);

    // ---- pointwise: split channels, multiply by H, repack ----
    for (int m = tid; m <= 8192; m += 1024) {
        int p1 = SWZ(rev14(m)), p2 = SWZ(rev14((NFULL - m) & (NFULL - 1)));
        float2 u = s[p1], v = s[p2];
        float2 X0 = make_float2(0.5f * (u.x + v.x), 0.5f * (u.y - v.y));
        float2 X1 = make_float2(0.5f * (u.y + v.y), 0.5f * (v.x - u.x));
        float2 Y0 = cmul(H0[m], X0);
        float2 Y1 = cmul(H1[m], X1);
        s[p1] = make_float2(Y0.x - Y1.y, Y0.y + Y1.x);                  // Y0 + i*Y1
        s[p2] = make_float2(Y0.x + Y1.y, Y1.x - Y0.y);                  // conj(Y0)+i*conj(Y1)
    }
    __syncthreads();

    // ---- inverse: middle phases, then P1' fused with output store ----
    inv_mid(s, tw);
    {
        const float sc = 1.0f / (float)NFULL;
        for (int g2 = 0; g2 < 4; g2++) {
            int G = tid + (g2 << 10);
            float2 x0 = s[SWZ(G)];
            float2 x1 = s[SWZ(G + 4096)];
            float2 x2 = s[SWZ(G + 8192)];
            float2 x3 = s[SWZ(G + 12288)];
            float2 t = tw[G];
            float2 w = make_float2(t.x, -t.y);       // e^{+2pi*i*G/16384}
            float2 w2 = csqr(w);
            dit_bf(x0, x1, w2);          // half=4096 stage
            dit_bf(x2, x3, w2);
            // half=8192 stage, keep only t<8192 outputs (causal conv tail dropped)
            float2 t0 = cmul(x2, w);
            float2 wp = make_float2(-w.y, w.x);
            float2 t1 = cmul(x3, wp);
            o0[G]        = f2b((x0.x + t0.x) * sc);
            o1[G]        = f2b((x0.y + t0.y) * sc);
            o0[G + 4096] = f2b((x1.x + t1.x) * sc);
            o1[G + 4096] = f2b((x1.y + t1.y) * sc);
        }
    }
}

// ---------------- bf16 MFMA GEMM: C = epi(A(M,K) @ Bt(N,K)^T + bias) ------------
// 128x128 tile, BK=32, 256 threads (4 waves, 2x2), 4x4 16x16x32 MFMA per wave.
// r10's 2-phase double-buffer (32KB LDS, 5 blocks/CU) — best measured variant.
#define BMT 128
#define BNT 128
#define BKT 32

template <int EPI>  // 0: silu->bf16   1: plain->f32   2: +res(bf16)->f32
__global__ __launch_bounds__(256) void gemm_bt(const bf16* __restrict__ A,
                                               const bf16* __restrict__ Bt,
                                               const float* __restrict__ bias,
                                               const bf16* __restrict__ res,
                                               void* __restrict__ out,
                                               int M, int N, int K) {
    __shared__ __align__(16) unsigned short As[2][BMT * BKT];
    __shared__ __align__(16) unsigned short Bs[2][BNT * BKT];
    int tid = threadIdx.x;
    int m0 = blockIdx.y * BMT, n0 = blockIdx.x * BNT;
    int lane = tid & 63, w = tid >> 6;
    int wm = w >> 1, wn = w & 1;
    int colq = lane & 15, quad = lane >> 4;

    f32x4 acc[4][4];
    for (int i = 0; i < 4; i++)
        for (int j = 0; j < 4; j++) acc[i][j] = (f32x4){0.f, 0.f, 0.f, 0.f};

    int lrow = lane >> 2, lcol = (lane & 3) * 8;
    int ch0 = w * 2, ch1 = w * 2 + 1;
    const bf16* ga0 = A + (size_t)(m0 + ch0 * 16 + lrow) * K + lcol;
    const bf16* ga1 = A + (size_t)(m0 + ch1 * 16 + lrow) * K + lcol;
    const bf16* gb0 = Bt + (size_t)(n0 + ch0 * 16 + lrow) * K + lcol;
    const bf16* gb1 = Bt + (size_t)(n0 + ch1 * 16 + lrow) * K + lcol;

    const int nk = K / BKT;
    // prologue: stage K-tile 0 into buffer 0
    glds16(ga0, &As[0][ch0 * 512]);
    glds16(ga1, &As[0][ch1 * 512]);
    glds16(gb0, &Bs[0][ch0 * 512]);
    glds16(gb1, &Bs[0][ch1 * 512]);
    __syncthreads();                 // vmcnt(0) drain: buffer 0 ready

    int cur = 0;
    for (int kb = 0; kb < nk; kb++) {
        // issue next-tile loads first; their flight hides under this tile's compute
        if (kb + 1 < nk) {
            int k1 = (kb + 1) * BKT;
            int nb = cur ^ 1;
            glds16(ga0 + k1, &As[nb][ch0 * 512]);
            glds16(ga1 + k1, &As[nb][ch1 * 512]);
            glds16(gb0 + k1, &Bs[nb][ch0 * 512]);
            glds16(gb1 + k1, &Bs[nb][ch1 * 512]);
        }
        bf16x8 af[4], bfr[4];
        for (int i = 0; i < 4; i++) {
            int mrow = wm * 64 + i * 16 + colq;
            af[i] = *(const bf16x8*)(&As[cur][mrow * BKT + quad * 8]);
            int nrow = wn * 64 + i * 16 + colq;
            bfr[i] = *(const bf16x8*)(&Bs[cur][nrow * BKT + quad * 8]);
        }
        for (int i = 0; i < 4; i++)
            for (int j = 0; j < 4; j++)
                acc[i][j] = __builtin_amdgcn_mfma_f32_16x16x32_bf16(af[i], bfr[j], acc[i][j], 0, 0, 0);
        __syncthreads();             // reads of buf[cur] done + next tile landed
        cur ^= 1;
    }
    for (int j = 0; j < 4; j++) {
        int n = n0 + wn * 64 + j * 16 + colq;
        float bv = bias[n];
        for (int i = 0; i < 4; i++) {
            int mbase = m0 + wm * 64 + i * 16 + quad * 4;
            for (int r = 0; r < 4; r++) {
                int m = mbase + r;
                float v = acc[i][j][r] + bv;
                size_t idx = (size_t)m * N + n;
                if (EPI == 0) {
                    ((bf16*)out)[idx] = f2b(v / (1.0f + expf(-v)));
                } else if (EPI == 1) {
                    ((float*)out)[idx] = v;
                } else {
                    ((float*)out)[idx] = v + b2f(res[idx]);
                }
            }
        }
    }
}

extern "C" void kernel_launch(void* const* d_in, const int* in_sizes, int n_in,
                              void* d_out, int out_size, void* d_ws, size_t ws_size,
                              hipStream_t stream) {
    (void)in_sizes; (void)n_in; (void)out_size; (void)ws_size;
    const float* z     = (const float*)d_in[0];
    const float* pos   = (const float*)d_in[1];
    const float* a     = (const float*)d_in[2];
    const float* w1p   = (const float*)d_in[3];
    const float* b1p   = (const float*)d_in[4];
    const float* w2p   = (const float*)d_in[5];
    const float* b2p   = (const float*)d_in[6];
    const float* w1    = (const float*)d_in[7];
    const float* b1    = (const float*)d_in[8];
    const float* w2    = (const float*)d_in[9];
    const float* b2    = (const float*)d_in[10];
    const float* gamma = (const float*)d_in[11];
    const float* beta  = (const float*)d_in[12];
    float* out = (float*)d_out;
    char* ws = (char*)d_ws;

    // ---- compact arena, 144,709,632 bytes total (lifetime-multiplexed) ----
    bf16*   w1T   = (bf16*)  (ws + 0);           //  4,718,592 (persistent)
    bf16*   w2T   = (bf16*)  (ws + 4718592);     //  4,718,592 (persistent)
    bf16*   w1pT  = (bf16*)  (ws + 9437184);     //  dead after pos-gemm1
    float2* twid  = (float2*)(ws + 9437184);     //  32KB twiddle table over dead w1pT
    bf16*   w2pT  = (bf16*)  (ws + 14155776);    //  dead after pos-gemm2
    bf16*   xlnT  = (bf16*)  (ws + 18874368);    // (B,D,L) bf16, 25.2M (ln..fft_conv)
    // R1 @44,040,192 (50,337,792): act1 (pos-FFN), then Hbuf (filter_fft..fft_conv)
    bf16*   act1  = (bf16*)  (ws + 44040192);    // (L,DFF) bf16
    float2* Hbuf  = (float2*)(ws + 44040192);    // (D,8193) cplx
    // R2 @94,377,984: two 25MB half-slots, time-multiplexed
    bf16*   xln   = (bf16*)  (ws + 94377984);    // (B,L,D) bf16 (ln..transpose)
    bf16*   posb  = (bf16*)  (ws + 119543808);   // (L,D) bf16 (cast..pos-gemm1)
    float*  h     = (float*) (ws + 119543808);   // (L,D) f32 (pos-gemm2..window); posb dead
    float*  whT   = (float*) (ws + 94377984);    // (D,L) f32 (window..filter_fft); xln dead
    bf16*   convT = (bf16*)  (ws + 119543808);   // (B,D,L) bf16 (fft_conv..residual); h dead
    bf16*   z2    = (bf16*)  (ws + 94377984);    // (B,L,D) bf16 (residual..end); whT dead
    bf16*   xb    = (bf16*)  (ws + 119543808);   // (B,L,D) bf16 (ln2..ffn); convT dead
    bf16*   act2  = (bf16*)  (ws + 18874368);    // (L,DFF) bf16 over dead xlnT+Hbuf

    dim3 tb(32, 8);
    // pre-transpose weights (K,N) f32 -> (N,K) bf16
    transpose_to_bf16<float><<<dim3(DFFQ / 32, DQ / 32, 1), tb, 0, stream>>>(w1p, w1pT, DQ, DFFQ);
    transpose_to_bf16<float><<<dim3(DQ / 32, DFFQ / 32, 1), tb, 0, stream>>>(w2p, w2pT, DFFQ, DQ);
    transpose_to_bf16<float><<<dim3(DFFQ / 32, DQ / 32, 1), tb, 0, stream>>>(w1, w1T, DQ, DFFQ);
    transpose_to_bf16<float><<<dim3(DQ / 32, DFFQ / 32, 1), tb, 0, stream>>>(w2, w2T, DFFQ, DQ);
    // pos f32 -> bf16
    cast_f32_bf16<<<(LQ * DQ / 4 + 255) / 256, 256, 0, stream>>>(pos, posb, LQ * DQ);
    // LN(z) -> xln, then transpose to (B,D,L)
    ln_kernel<float><<<2 * LQ, 256, 0, stream>>>(z, gamma, beta, xln);
    transpose_to_bf16<bf16><<<dim3(DQ / 32, LQ / 32, 2), tb, 0, stream>>>(xln, xlnT, LQ, DQ);
    // pos FFN -> h
    gemm_bt<0><<<dim3(DFFQ / BNT, LQ / BMT), 256, 0, stream>>>(posb, w1pT, b1p, nullptr, act1, LQ, DFFQ, DQ);
    // twiddle table into the now-dead w1pT slot
    gen_twiddle<<<16, 256, 0, stream>>>(twid);
    gemm_bt<1><<<dim3(DQ / BNT, LQ / BMT), 256, 0, stream>>>(act1, w2pT, b2p, nullptr, h, LQ, DQ, DFFQ);
    // window * h, transposed -> whT
    transpose_window<<<dim3(DQ / 32, LQ / 32), tb, 0, stream>>>(h, a, whT);
    // filter spectrum -> Hbuf (overwrites act1, dead)
    filter_fft<<<DQ / 2, 1024, 0, stream>>>(whT, twid, Hbuf);
    // fused FFT conv -> convT
    fft_conv<<<2 * (DQ / 2), 1024, 0, stream>>>(xlnT, Hbuf, twid, convT);
    // z2 = conv + z (overwrites whT slot, dead)
    transpose_residual<<<dim3(LQ / 32, DQ / 32, 2), tb, 0, stream>>>(convT, z, z2);
    // LN(z2) -> xb (overwrites convT slot, dead)
    ln_kernel<bf16><<<2 * LQ, 256, 0, stream>>>(z2, gamma, beta, xb);
    // main FFN + residual -> out, batch-halved so act2 fits
    for (int b = 0; b < 2; b++) {
        const bf16* xbh = xb + (size_t)b * LQ * DQ;
        const bf16* z2h = z2 + (size_t)b * LQ * DQ;
        float* outh = out + (size_t)b * LQ * DQ;
        gemm_bt<0><<<dim3(DFFQ / BNT, LQ / BMT), 256, 0, stream>>>(xbh, w1T, b1, nullptr, act2, LQ, DFFQ, DQ);
        gemm_bt<2><<<dim3(DQ / BNT, LQ / BMT), 256, 0, stream>>>(act2, w2T, b2, z2h, outh, LQ, DQ, DFFQ);
    }
}